// Round 4
// baseline (18088.425 us; speedup 1.0000x reference)
//
#include <hip/hip_runtime.h>
#include <math.h>

#define BB 8
#define NN 512
#define DD 512
#define HH 8
#define DHH 64
#define FFF 2048
#define MEMM 4096
#define TOPKK 32
#define DEPTHH 6
#define NT (BB*NN)   /* 4096 tokens */

// ---------------- LayerNorm ----------------
__global__ __launch_bounds__(256) void ln_kernel(const float* __restrict__ xin,
                                                 const float* __restrict__ g,
                                                 const float* __restrict__ bt,
                                                 float* __restrict__ out) {
  __shared__ float red[4];
  int tok = blockIdx.x;
  const float* xr = xin + (size_t)tok * DD;
  int t = threadIdx.x;
  float v0 = xr[t], v1 = xr[t + 256];
  float s = v0 + v1;
#pragma unroll
  for (int m = 32; m; m >>= 1) s += __shfl_xor(s, m, 64);
  if ((t & 63) == 0) red[t >> 6] = s;
  __syncthreads();
  float mean = (red[0] + red[1] + red[2] + red[3]) * (1.0f / 512.0f);
  float d0 = v0 - mean, d1 = v1 - mean;
  float vv = d0 * d0 + d1 * d1;
#pragma unroll
  for (int m = 32; m; m >>= 1) vv += __shfl_xor(vv, m, 64);
  __syncthreads();
  if ((t & 63) == 0) red[t >> 6] = vv;
  __syncthreads();
  float var = (red[0] + red[1] + red[2] + red[3]) * (1.0f / 512.0f);
  float inv = rsqrtf(var + 1e-5f);
  out[(size_t)tok * DD + t]       = d0 * inv * g[t] + bt[t];
  out[(size_t)tok * DD + t + 256] = d1 * inv * g[t + 256] + bt[t + 256];
}

__device__ inline float gelu_f(float x) {
  float x3 = x * x * x;
  return 0.5f * x * (1.0f + tanhf(0.7978845608028654f * (x + 0.044715f * x3)));
}

// ---------------- SGEMM: C = A(MxK) @ B(KxN) [EPI: 0 none, 1 gelu, 2 +R] ----
template <int EPI>
__global__ __launch_bounds__(256) void gemm_kernel(const float* __restrict__ A,
                                                   const float* __restrict__ Bm,
                                                   const float* __restrict__ R,
                                                   float* __restrict__ C,
                                                   int M, int Nc, int K) {
  __shared__ float As[16][68];
  __shared__ float Bs[16][68];
  int tx = threadIdx.x & 15, ty = threadIdx.x >> 4;
  int bm = blockIdx.y, bn = blockIdx.x;
  int r0 = ty * 4, c0 = tx * 4;
  float acc[4][4] = {};
  for (int kt = 0; kt < K; kt += 16) {
    {  // A tile 64x16 -> As[k][row] (transposed)
      int row = threadIdx.x >> 2;
      int kk = (threadIdx.x & 3) * 4;
      float4 a4 = *(const float4*)(A + (size_t)(bm * 64 + row) * K + kt + kk);
      As[kk + 0][row] = a4.x; As[kk + 1][row] = a4.y;
      As[kk + 2][row] = a4.z; As[kk + 3][row] = a4.w;
    }
    {  // B tile 16x64 -> Bs[k][col]
      int kk = threadIdx.x >> 4;
      int col = (threadIdx.x & 15) * 4;
      *(float4*)&Bs[kk][col] = *(const float4*)(Bm + (size_t)(kt + kk) * Nc + bn * 64 + col);
    }
    __syncthreads();
#pragma unroll
    for (int kk = 0; kk < 16; kk++) {
      float4 a4 = *(const float4*)&As[kk][r0];
      float4 b4 = *(const float4*)&Bs[kk][c0];
      float a_[4] = {a4.x, a4.y, a4.z, a4.w};
      float b_[4] = {b4.x, b4.y, b4.z, b4.w};
#pragma unroll
      for (int i = 0; i < 4; i++)
#pragma unroll
        for (int j = 0; j < 4; j++) acc[i][j] += a_[i] * b_[j];
    }
    __syncthreads();
  }
#pragma unroll
  for (int i = 0; i < 4; i++) {
    size_t off = (size_t)(bm * 64 + r0 + i) * Nc + bn * 64 + c0;
    float4 o;
    if (EPI == 1) {
      o.x = gelu_f(acc[i][0]); o.y = gelu_f(acc[i][1]);
      o.z = gelu_f(acc[i][2]); o.w = gelu_f(acc[i][3]);
    } else if (EPI == 2) {
      float4 rv = *(const float4*)(R + off);
      o.x = rv.x + acc[i][0]; o.y = rv.y + acc[i][1];
      o.z = rv.z + acc[i][2]; o.w = rv.w + acc[i][3];
    } else {
      o.x = acc[i][0]; o.y = acc[i][1]; o.z = acc[i][2]; o.w = acc[i][3];
    }
    *(float4*)(C + off) = o;
  }
}

// ---------------- fused q@mem_k + top-32, register-resident selection -------
// grid (N/64, H, B) = (8,8,8), block 256 = 64 rows x 4 candidate-partitions.
// Each lane keeps its (row, quarter)'s top-32 in REGISTERS (fully unrolled
// replace-min: pure VALU, no LDS latency chains). Final 4-way merge per row
// through LDS once at the end.
__device__ __forceinline__ void insert32(float (&rtv)[32], int (&rti)[32],
                                         float sv, int idx, float& thr) {
  float mv = rtv[0], mv2 = INFINITY;
  int mi = 0;
#pragma unroll
  for (int k = 1; k < 32; k++) {
    float v = rtv[k];
    bool lt = v < mv;
    mv2 = lt ? mv : fminf(mv2, v);
    mv = lt ? v : mv;
    mi = lt ? k : mi;
  }
#pragma unroll
  for (int k = 0; k < 32; k++) {
    bool hit = (k == mi);
    rtv[k] = hit ? sv : rtv[k];
    rti[k] = hit ? idx : rti[k];
  }
  thr = fminf(mv2, sv);
}

__global__ __launch_bounds__(256, 2) void knn_topk_kernel(const float* __restrict__ q,
                                                          const float* __restrict__ mem_k,
                                                          float* __restrict__ topv,
                                                          int* __restrict__ topi) {
  __shared__ float qs[64][68];    // [row][d]
  __shared__ float ks[128][68];   // [cand][d]; reused as scores [row][136] + merge vals
  int it = blockIdx.x, h = blockIdx.y, b = blockIdx.z;
  int t = threadIdx.x;
  const float scale = 0.125f;
  {  // stage q tile 64x64 (coalesced)
    int row = t >> 2;
    int col = (t & 3) * 16;
    const float* qp = q + ((size_t)(b * NN) + it * 64 + row) * DD + h * DHH + col;
#pragma unroll
    for (int j = 0; j < 16; j += 4)
      *(float4*)&qs[row][col + j] = *(const float4*)(qp + j);
  }
  int tx = t & 15, ty = t >> 4;
  int r0 = ty * 4, c0 = tx * 8;
  int r = t & 63, w = t >> 6;
  float* scb = &ks[0][0];              // scores: [64][136] overlay of ks
  float* srow = scb + 136 * r;
  int pbase = 32 * w;                  // this lane's candidate quarter
  float rtv[32]; int rti[32];
  float thr = -INFINITY;
  const float* kbase = mem_k + (size_t)b * MEMM * DHH;

  for (int mt = 0; mt < MEMM; mt += 128) {
    __syncthreads();  // selection of prev tile done before restaging ks
    {  // stage mem_k tile 128x64 (coalesced, no transpose)
      const float* kp = kbase + (size_t)mt * DHH;
#pragma unroll
      for (int i = 0; i < 8; i++) {
        int lin = i * 256 + t;
        int row = lin >> 4, col = (lin & 15) * 4;
        *(float4*)&ks[row][col] = *(const float4*)(kp + (size_t)row * DHH + col);
      }
    }
    __syncthreads();
    float acc[4][8] = {};
#pragma unroll
    for (int d4 = 0; d4 < 64; d4 += 4) {  // all LDS reads broadcast (conflict-free)
      float4 aa[4], bb[8];
#pragma unroll
      for (int i2 = 0; i2 < 4; i2++) aa[i2] = *(const float4*)&qs[r0 + i2][d4];
#pragma unroll
      for (int j2 = 0; j2 < 8; j2++) bb[j2] = *(const float4*)&ks[c0 + j2][d4];
#pragma unroll
      for (int i2 = 0; i2 < 4; i2++)
#pragma unroll
        for (int j2 = 0; j2 < 8; j2++)
          acc[i2][j2] += aa[i2].x * bb[j2].x + aa[i2].y * bb[j2].y +
                         aa[i2].z * bb[j2].z + aa[i2].w * bb[j2].w;
    }
    __syncthreads();  // all waves done reading ks before score overwrite
#pragma unroll
    for (int i2 = 0; i2 < 4; i2++) {
      float* p = scb + (size_t)(r0 + i2) * 136 + c0;
#pragma unroll
      for (int j2 = 0; j2 < 8; j2 += 4) {
        float4 o;
        o.x = acc[i2][j2 + 0] * scale; o.y = acc[i2][j2 + 1] * scale;
        o.z = acc[i2][j2 + 2] * scale; o.w = acc[i2][j2 + 3] * scale;
        *(float4*)(p + j2) = o;
      }
    }
    __syncthreads();
    // selection: lane (r, w) scans its 32 candidates (rotated: (9r+c)%32 banks)
    if (mt == 0) {  // warm start: fill slots directly
#pragma unroll
      for (int k = 0; k < 32; k++) {
        int cc = (k + r) & 31;
        rtv[k] = srow[pbase + cc];
        rti[k] = pbase + cc;
      }
      float mn = rtv[0];
#pragma unroll
      for (int k = 1; k < 32; k++) mn = fminf(mn, rtv[k]);
      thr = mn;
    } else {
#pragma unroll 1
      for (int c = 0; c < 32; c++) {
        int cc = (c + r) & 31;
        float sv = srow[pbase + cc];
        if (sv > thr) insert32(rtv, rti, sv, mt + pbase + cc, thr);
      }
    }
  }
  __syncthreads();  // last selection reads done before merge dump overwrites
  {  // dump partial lists: vals into scb, idx (u16) into qs region
    unsigned short* mgi = (unsigned short*)&qs[0][0];  // [64][136] u16
#pragma unroll
    for (int k = 0; k < 32; k++) {
      int cc = (k + r) & 31;
      scb[136 * r + pbase + cc] = rtv[k];
      mgi[136 * r + pbase + cc] = (unsigned short)rti[k];
    }
  }
  __syncthreads();
  if (t < 64) {  // wave 0: lane r merges parts 1..3 into its part-0 registers
    const unsigned short* mgi = (const unsigned short*)&qs[0][0];
#pragma unroll 1
    for (int c = 0; c < 96; c++) {
      int cc = c + (r & 31); if (cc >= 96) cc -= 96;
      float sv = scb[136 * r + 32 + cc];
      if (sv > thr) insert32(rtv, rti, sv, (int)mgi[136 * r + 32 + cc], thr);
    }
    size_t rowg = ((size_t)b * HH + h) * NN + it * 64 + r;
#pragma unroll
    for (int k = 0; k < 32; k++) {
      topv[rowg * TOPKK + k] = rtv[k];
      topi[rowg * TOPKK + k] = rti[k];
    }
  }
}

// ---------------- flash attention (+ optional kNN memory logits) ----------
// grid (N/64, H, B), block 256. ao layout [b][i][h*64+d]
__global__ __launch_bounds__(256) void attn_kernel(const float* __restrict__ q,
                                                   const float* __restrict__ k,
                                                   const float* __restrict__ v,
                                                   float* __restrict__ ao,
                                                   const float* __restrict__ topv,
                                                   const int* __restrict__ topi,
                                                   const float* __restrict__ mem_v,
                                                   int knn) {
  int bi = blockIdx.x, h = blockIdx.y, b = blockIdx.z;
  __shared__ float ks[64][64];
  __shared__ float vs[64][64];
  __shared__ float sc[64][65];
  __shared__ float marr[64], larr[64], aarr[64];
  __shared__ int pidx[64][33];
  const float scale = 0.125f;
  int t = threadIdx.x;
  int r = t & 63;   // row role
  int w = t >> 6;   // wave: phase1 col-group / phase2 d-group
  int i0 = bi * 64;
  int iglob = i0 + r;

  float qreg[64];
  {
    const float* qp = q + ((size_t)(b * NN) + iglob) * DD + h * DHH;
#pragma unroll
    for (int d4 = 0; d4 < 64; d4 += 4) {
      float4 a = *(const float4*)(qp + d4);
      qreg[d4] = a.x * scale; qreg[d4 + 1] = a.y * scale;
      qreg[d4 + 2] = a.z * scale; qreg[d4 + 3] = a.w * scale;
    }
  }
  if (t < 64) { marr[t] = -INFINITY; larr[t] = 0.f; }
  float acc[16] = {};
  int ntiles = bi + 1;
  for (int jt = 0; jt < ntiles; jt++) {
    __syncthreads();
#pragma unroll
    for (int i = 0; i < 4; i++) {  // load K,V tiles
      int lin = i * 256 + t;
      int row = lin >> 4, col = (lin & 15) * 4;
      size_t goff = ((size_t)(b * NN) + jt * 64 + row) * DD + h * DHH + col;
      *(float4*)&ks[row][col] = *(const float4*)(k + goff);
      *(float4*)&vs[row][col] = *(const float4*)(v + goff);
    }
    __syncthreads();
    {  // phase1: scores row r, cols w*16..+15
      float s[16] = {};
#pragma unroll
      for (int d4 = 0; d4 < 64; d4 += 4) {
#pragma unroll
        for (int j = 0; j < 16; j++) {
          float4 k4 = *(const float4*)&ks[w * 16 + j][d4];
          s[j] += qreg[d4] * k4.x + qreg[d4 + 1] * k4.y +
                  qreg[d4 + 2] * k4.z + qreg[d4 + 3] * k4.w;
        }
      }
#pragma unroll
      for (int j = 0; j < 16; j++) sc[r][w * 16 + j] = s[j];
    }
    __syncthreads();
    {  // online softmax: wave w owns rows w*16..+15
      int lane = t & 63;
      for (int rr = w * 16; rr < w * 16 + 16; rr++) {
        int ig = i0 + rr;
        int jg = jt * 64 + lane;
        float s = sc[rr][lane];
        if (jg > ig) s = -INFINITY;
        float m_old = marr[rr];
        float tm = s;
#pragma unroll
        for (int m = 32; m; m >>= 1) tm = fmaxf(tm, __shfl_xor(tm, m, 64));
        float m_new = fmaxf(m_old, tm);
        float p = __expf(s - m_new);
        float ts = p;
#pragma unroll
        for (int m = 32; m; m >>= 1) ts += __shfl_xor(ts, m, 64);
        float alpha = __expf(m_old - m_new);
        sc[rr][lane] = p;
        if (lane == 0) {
          marr[rr] = m_new; larr[rr] = larr[rr] * alpha + ts; aarr[rr] = alpha;
        }
      }
    }
    __syncthreads();
    {  // phase2: acc[r][w*16..+15] += P @ V
      float al = aarr[r];
#pragma unroll
      for (int dd = 0; dd < 16; dd++) acc[dd] *= al;
      for (int j = 0; j < 64; j++) {
        float p = sc[r][j];
        const float* vrow = &vs[j][w * 16];
#pragma unroll
        for (int dd = 0; dd < 16; dd += 4) {
          float4 v4 = *(const float4*)(vrow + dd);
          acc[dd] += p * v4.x; acc[dd + 1] += p * v4.y;
          acc[dd + 2] += p * v4.z; acc[dd + 3] += p * v4.w;
        }
      }
    }
  }
  if (knn) {
    __syncthreads();
    {  // memory logits (already scaled in topk kernel)
      int lane = t & 63;
      size_t rowbase = ((size_t)b * HH + h) * NN + i0;
      for (int rr = w * 16; rr < w * 16 + 16; rr++) {
        float s = (lane < TOPKK) ? topv[(rowbase + rr) * TOPKK + lane] : -INFINITY;
        float m_old = marr[rr];
        float tm = s;
#pragma unroll
        for (int m = 32; m; m >>= 1) tm = fmaxf(tm, __shfl_xor(tm, m, 64));
        float m_new = fmaxf(m_old, tm);
        float p = __expf(s - m_new);
        float ts = p;
#pragma unroll
        for (int m = 32; m; m >>= 1) ts += __shfl_xor(ts, m, 64);
        float alpha = __expf(m_old - m_new);
        sc[rr][lane] = p;
        if (lane < TOPKK) pidx[rr][lane] = topi[(rowbase + rr) * TOPKK + lane];
        if (lane == 0) {
          marr[rr] = m_new; larr[rr] = larr[rr] * alpha + ts; aarr[rr] = alpha;
        }
      }
    }
    __syncthreads();
    {
      float al = aarr[r];
#pragma unroll
      for (int dd = 0; dd < 16; dd++) acc[dd] *= al;
      const float* mvb = mem_v + (size_t)b * MEMM * DHH;
      for (int kk = 0; kk < TOPKK; kk++) {
        float p = sc[r][kk];
        const float* mrow = mvb + (size_t)pidx[r][kk] * DHH + w * 16;
#pragma unroll
        for (int dd = 0; dd < 16; dd += 4) {
          float4 m4 = *(const float4*)(mrow + dd);
          acc[dd] += p * m4.x; acc[dd + 1] += p * m4.y;
          acc[dd + 2] += p * m4.z; acc[dd + 3] += p * m4.w;
        }
      }
    }
  }
  {  // epilogue: out = acc / l
    float linv = 1.0f / larr[r];
    float* aop = ao + ((size_t)(b * NN) + iglob) * DD + h * DHH + w * 16;
#pragma unroll
    for (int dd = 0; dd < 16; dd += 4) {
      float4 o;
      o.x = acc[dd] * linv; o.y = acc[dd + 1] * linv;
      o.z = acc[dd + 2] * linv; o.w = acc[dd + 3] * linv;
      *(float4*)(aop + dd) = o;
    }
  }
}

// ---------------- host ----------------
extern "C" void kernel_launch(void* const* d_in, const int* in_sizes, int n_in,
                              void* d_out, int out_size, void* d_ws, size_t ws_size,
                              hipStream_t stream) {
  const float* x_in  = (const float*)d_in[0];
  const float* Wq    = (const float*)d_in[1];
  const float* Wk    = (const float*)d_in[2];
  const float* Wv    = (const float*)d_in[3];
  const float* Wo    = (const float*)d_in[4];
  const float* ln1_s = (const float*)d_in[5];
  const float* ln1_b = (const float*)d_in[6];
  const float* ln2_s = (const float*)d_in[7];
  const float* ln2_b = (const float*)d_in[8];
  const float* W1    = (const float*)d_in[9];
  const float* W2    = (const float*)d_in[10];
  const float* lnf_s = (const float*)d_in[11];
  const float* lnf_b = (const float*)d_in[12];
  const float* mem_k = (const float*)d_in[13];
  const float* mem_v = (const float*)d_in[14];

  // workspace layout (floats), total 14,680,064 floats = 58.72 MB:
  //  xb   [0        .. 2097152)   residual stream
  //  hb   [2097152  .. 4194304)   LN output
  //  qb/kb/vb/aob [4194304 .. 12582912)  (ffb 32MB aliases these during FFN)
  //  tvb  [12582912 .. 13631488)  top-k values  (B*H*N*TOPK = 1M elems)
  //  tib  [13631488 .. 14680064)  top-k indices (1M elems)
  float* ws  = (float*)d_ws;
  float* xb  = ws;
  float* hb  = ws + 2097152;
  float* qb  = ws + 4194304;
  float* kb  = ws + 6291456;
  float* vb  = ws + 8388608;
  float* aob = ws + 10485760;
  float* ffb = ws + 4194304;           // aliases qb..aob
  float* tvb = ws + 12582912;
  int*   tib = (int*)(ws + 13631488);

  dim3 blk(256);
  const size_t DD2 = (size_t)DD * DD;
  for (int l = 0; l < DEPTHH; l++) {
    const float* xcur = (l == 0) ? x_in : xb;
    ln_kernel<<<NT, blk, 0, stream>>>(xcur, ln1_s + l * DD, ln1_b + l * DD, hb);
    gemm_kernel<0><<<dim3(8, 64), blk, 0, stream>>>(hb, Wq + l * DD2, nullptr, qb, NT, DD, DD);
    gemm_kernel<0><<<dim3(8, 64), blk, 0, stream>>>(hb, Wk + l * DD2, nullptr, kb, NT, DD, DD);
    gemm_kernel<0><<<dim3(8, 64), blk, 0, stream>>>(hb, Wv + l * DD2, nullptr, vb, NT, DD, DD);
    int mi = (l == 3) ? 0 : ((l == 4) ? 1 : -1);
    if (mi >= 0)
      knn_topk_kernel<<<dim3(8, 8, 8), blk, 0, stream>>>(
          qb, mem_k + (size_t)mi * BB * MEMM * DHH, tvb, tib);
    attn_kernel<<<dim3(8, 8, 8), blk, 0, stream>>>(
        qb, kb, vb, aob, tvb, tib,
        mem_v + (size_t)(mi < 0 ? 0 : mi) * BB * MEMM * DHH, mi >= 0 ? 1 : 0);
    gemm_kernel<2><<<dim3(8, 64), blk, 0, stream>>>(aob, Wo + l * DD2, xcur, xb, NT, DD, DD);
    ln_kernel<<<NT, blk, 0, stream>>>(xb, ln2_s + l * DD, ln2_b + l * DD, hb);
    gemm_kernel<1><<<dim3(32, 64), blk, 0, stream>>>(
        hb, W1 + (size_t)l * DD * FFF, nullptr, ffb, NT, FFF, DD);
    gemm_kernel<2><<<dim3(8, 64), blk, 0, stream>>>(
        ffb, W2 + (size_t)l * FFF * DD, xb, xb, NT, DD, FFF);
  }
  ln_kernel<<<NT, blk, 0, stream>>>(xb, lnf_s, lnf_b, (float*)d_out);
}

// Round 5
// 8670.930 us; speedup vs baseline: 2.0861x; 2.0861x over previous
//
#include <hip/hip_runtime.h>
#include <math.h>

#define BB 8
#define NN 512
#define DD 512
#define HH 8
#define DHH 64
#define FFF 2048
#define MEMM 4096
#define TOPKK 32
#define DEPTHH 6
#define NT (BB*NN)   /* 4096 tokens */

// ---------------- LayerNorm ----------------
__global__ __launch_bounds__(256) void ln_kernel(const float* __restrict__ xin,
                                                 const float* __restrict__ g,
                                                 const float* __restrict__ bt,
                                                 float* __restrict__ out) {
  __shared__ float red[4];
  int tok = blockIdx.x;
  const float* xr = xin + (size_t)tok * DD;
  int t = threadIdx.x;
  float v0 = xr[t], v1 = xr[t + 256];
  float s = v0 + v1;
#pragma unroll
  for (int m = 32; m; m >>= 1) s += __shfl_xor(s, m, 64);
  if ((t & 63) == 0) red[t >> 6] = s;
  __syncthreads();
  float mean = (red[0] + red[1] + red[2] + red[3]) * (1.0f / 512.0f);
  float d0 = v0 - mean, d1 = v1 - mean;
  float vv = d0 * d0 + d1 * d1;
#pragma unroll
  for (int m = 32; m; m >>= 1) vv += __shfl_xor(vv, m, 64);
  __syncthreads();
  if ((t & 63) == 0) red[t >> 6] = vv;
  __syncthreads();
  float var = (red[0] + red[1] + red[2] + red[3]) * (1.0f / 512.0f);
  float inv = rsqrtf(var + 1e-5f);
  out[(size_t)tok * DD + t]       = d0 * inv * g[t] + bt[t];
  out[(size_t)tok * DD + t + 256] = d1 * inv * g[t + 256] + bt[t + 256];
}

__device__ inline float gelu_f(float x) {
  float x3 = x * x * x;
  return 0.5f * x * (1.0f + tanhf(0.7978845608028654f * (x + 0.044715f * x3)));
}

// ---------------- SGEMM: C = A(MxK) @ B(KxN) [EPI: 0 none, 1 gelu, 2 +R] ----
template <int EPI>
__global__ __launch_bounds__(256) void gemm_kernel(const float* __restrict__ A,
                                                   const float* __restrict__ Bm,
                                                   const float* __restrict__ R,
                                                   float* __restrict__ C,
                                                   int M, int Nc, int K) {
  __shared__ float As[16][68];
  __shared__ float Bs[16][68];
  int tx = threadIdx.x & 15, ty = threadIdx.x >> 4;
  int bm = blockIdx.y, bn = blockIdx.x;
  int r0 = ty * 4, c0 = tx * 4;
  float acc[4][4] = {};
  for (int kt = 0; kt < K; kt += 16) {
    {  // A tile 64x16 -> As[k][row] (transposed)
      int row = threadIdx.x >> 2;
      int kk = (threadIdx.x & 3) * 4;
      float4 a4 = *(const float4*)(A + (size_t)(bm * 64 + row) * K + kt + kk);
      As[kk + 0][row] = a4.x; As[kk + 1][row] = a4.y;
      As[kk + 2][row] = a4.z; As[kk + 3][row] = a4.w;
    }
    {  // B tile 16x64 -> Bs[k][col]
      int kk = threadIdx.x >> 4;
      int col = (threadIdx.x & 15) * 4;
      *(float4*)&Bs[kk][col] = *(const float4*)(Bm + (size_t)(kt + kk) * Nc + bn * 64 + col);
    }
    __syncthreads();
#pragma unroll
    for (int kk = 0; kk < 16; kk++) {
      float4 a4 = *(const float4*)&As[kk][r0];
      float4 b4 = *(const float4*)&Bs[kk][c0];
      float a_[4] = {a4.x, a4.y, a4.z, a4.w};
      float b_[4] = {b4.x, b4.y, b4.z, b4.w};
#pragma unroll
      for (int i = 0; i < 4; i++)
#pragma unroll
        for (int j = 0; j < 4; j++) acc[i][j] += a_[i] * b_[j];
    }
    __syncthreads();
  }
#pragma unroll
  for (int i = 0; i < 4; i++) {
    size_t off = (size_t)(bm * 64 + r0 + i) * Nc + bn * 64 + c0;
    float4 o;
    if (EPI == 1) {
      o.x = gelu_f(acc[i][0]); o.y = gelu_f(acc[i][1]);
      o.z = gelu_f(acc[i][2]); o.w = gelu_f(acc[i][3]);
    } else if (EPI == 2) {
      float4 rv = *(const float4*)(R + off);
      o.x = rv.x + acc[i][0]; o.y = rv.y + acc[i][1];
      o.z = rv.z + acc[i][2]; o.w = rv.w + acc[i][3];
    } else {
      o.x = acc[i][0]; o.y = acc[i][1]; o.z = acc[i][2]; o.w = acc[i][3];
    }
    *(float4*)(C + off) = o;
  }
}

// ---------------- fused q@mem_k + top-32 ----------------
// grid (N/32, H, B) = (16,8,8), block 256 = 32 rows x 8 candidate-partitions.
// Register-resident (value,index) top-32 per lane (~112 VGPR, no spill).
// Row-level shared bound B (max of the 8 partitions' running 32nd values,
// provably <= final tau) prunes inserts. All LDS patterns <=2-way.
__device__ __forceinline__ void insert32vi(float (&rtv)[32], int (&rti)[32],
                                           float sv, int idx, float& thr) {
  float mv = rtv[0], mv2 = INFINITY;
  int mi = 0;
#pragma unroll
  for (int k = 1; k < 32; k++) {
    float v = rtv[k];
    bool lt = v < mv;
    mv2 = lt ? mv : fminf(mv2, v);
    mv = lt ? v : mv;
    mi = lt ? k : mi;
  }
#pragma unroll
  for (int k = 0; k < 32; k++) {
    bool hit = (k == mi);
    rtv[k] = hit ? sv : rtv[k];
    rti[k] = hit ? idx : rti[k];
  }
  thr = fminf(mv2, sv);
}

__global__ __launch_bounds__(256) void knn_topk_kernel(const float* __restrict__ q,
                                                       const float* __restrict__ mem_k,
                                                       float* __restrict__ topv,
                                                       int* __restrict__ topi) {
  __shared__ float qs[32][68];            // [row][d]
  __shared__ float ks[128][68];           // [cand][d]; overlaid: scores [32][132], merge vals [32][260]
  __shared__ unsigned short midx[32 * 260];  // merge indices (u16, cand < 4096)
  __shared__ float rthr[8][32];           // per-(part,row) running 32nd value
  int it = blockIdx.x, h = blockIdx.y, b = blockIdx.z;
  int t = threadIdx.x;
  const float scale = 0.125f;
  {  // stage q tile 32x64 (coalesced)
    int row = t >> 3;
    int col = (t & 7) * 8;
    const float* qp = q + ((size_t)(b * NN) + it * 32 + row) * DD + h * DHH + col;
    *(float4*)&qs[row][col]     = *(const float4*)qp;
    *(float4*)&qs[row][col + 4] = *(const float4*)(qp + 4);
  }
  int tx = t & 15, ty = t >> 4;           // GEMM roles: rows 2ty..2ty+1, cols tx+16j
  int r = t & 31, p = t >> 5;             // selection roles: row r, partition p
  rthr[p][r] = -INFINITY;
  float rtv[32]; int rti[32];
#pragma unroll
  for (int k = 0; k < 32; k++) { rtv[k] = -INFINITY; rti[k] = 0; }
  float thr = -INFINITY;
  float* scb = &ks[0][0];                 // score overlay, stride 132
  const float* kbase = mem_k + (size_t)b * MEMM * DHH;

  for (int mt = 0; mt < MEMM; mt += 128) {
    __syncthreads();  // prev selection reads of scb done before restaging ks
    {  // stage mem_k tile 128x64 (coalesced)
      const float* kp = kbase + (size_t)mt * DHH;
#pragma unroll
      for (int i = 0; i < 8; i++) {
        int lin = i * 256 + t;
        int row = lin >> 4, col = (lin & 15) * 4;
        *(float4*)&ks[row][col] = *(const float4*)(kp + (size_t)row * DHH + col);
      }
    }
    __syncthreads();
    float acc[2][8] = {};
#pragma unroll 4
    for (int d4 = 0; d4 < 64; d4 += 4) {
      float4 a0 = *(const float4*)&qs[2 * ty][d4];
      float4 a1 = *(const float4*)&qs[2 * ty + 1][d4];
#pragma unroll
      for (int j = 0; j < 8; j++) {
        float4 bv = *(const float4*)&ks[tx + 16 * j][d4];  // 2-way spread, bcast over ty
        acc[0][j] += a0.x * bv.x + a0.y * bv.y + a0.z * bv.z + a0.w * bv.w;
        acc[1][j] += a1.x * bv.x + a1.y * bv.y + a1.z * bv.z + a1.w * bv.w;
      }
    }
    __syncthreads();  // all waves done reading ks before score overwrite
#pragma unroll
    for (int i2 = 0; i2 < 2; i2++)
#pragma unroll
      for (int j = 0; j < 8; j++)
        scb[(size_t)(2 * ty + i2) * 132 + tx + 16 * j] = acc[i2][j] * scale;
    __syncthreads();
    {  // selection: lane (r,p) scans its 16 cols, rotated reads (2-way)
      float B2 = rthr[0][r];
#pragma unroll
      for (int j = 1; j < 8; j++) B2 = fmaxf(B2, rthr[j][r]);
      const float* srow = scb + (size_t)132 * r + 16 * p;
#pragma unroll 1
      for (int c = 0; c < 16; c++) {
        int cc = (c + r) & 15;
        float sv = srow[cc];
        if (sv > fmaxf(thr, B2))
          insert32vi(rtv, rti, sv, mt + 16 * p + cc, thr);
      }
      rthr[p][r] = thr;
    }
  }
  __syncthreads();  // selection reads done before merge-dump overwrites scb
  {  // dump all partitions: vals stride-260 overlay, idx u16
    float* mvals = &ks[0][0];
#pragma unroll
    for (int k = 0; k < 32; k++) {
      int cc = (k + r) & 31;
      mvals[(size_t)260 * r + 32 * p + cc] = rtv[k];
      midx[(size_t)260 * r + 32 * p + cc] = (unsigned short)rti[k];
    }
  }
  __syncthreads();
  if (t < 32) {  // lane r merges partitions 1..7 into its part-0 registers
    const float* mvals = &ks[0][0];
#pragma unroll 1
    for (int c = 0; c < 224; c++) {
      int cc = c + r; if (cc >= 224) cc -= 224;
      float sv = mvals[(size_t)260 * r + 32 + cc];
      if (sv > thr)
        insert32vi(rtv, rti, sv, (int)midx[(size_t)260 * r + 32 + cc], thr);
    }
    size_t rowg = ((size_t)b * HH + h) * NN + it * 32 + r;
#pragma unroll
    for (int k = 0; k < 32; k++) {
      topv[rowg * TOPKK + k] = rtv[k];
      topi[rowg * TOPKK + k] = rti[k];
    }
  }
}

// ---------------- flash attention (+ optional kNN memory logits) ----------
// grid (N/64, H, B), block 256. ao layout [b][i][h*64+d]
__global__ __launch_bounds__(256) void attn_kernel(const float* __restrict__ q,
                                                   const float* __restrict__ k,
                                                   const float* __restrict__ v,
                                                   float* __restrict__ ao,
                                                   const float* __restrict__ topv,
                                                   const int* __restrict__ topi,
                                                   const float* __restrict__ mem_v,
                                                   int knn) {
  int bi = blockIdx.x, h = blockIdx.y, b = blockIdx.z;
  __shared__ float ks[64][64];
  __shared__ float vs[64][64];
  __shared__ float sc[64][65];
  __shared__ float marr[64], larr[64], aarr[64];
  __shared__ int pidx[64][33];
  const float scale = 0.125f;
  int t = threadIdx.x;
  int r = t & 63;   // row role
  int w = t >> 6;   // wave: phase1 col-group / phase2 d-group
  int i0 = bi * 64;
  int iglob = i0 + r;

  float qreg[64];
  {
    const float* qp = q + ((size_t)(b * NN) + iglob) * DD + h * DHH;
#pragma unroll
    for (int d4 = 0; d4 < 64; d4 += 4) {
      float4 a = *(const float4*)(qp + d4);
      qreg[d4] = a.x * scale; qreg[d4 + 1] = a.y * scale;
      qreg[d4 + 2] = a.z * scale; qreg[d4 + 3] = a.w * scale;
    }
  }
  if (t < 64) { marr[t] = -INFINITY; larr[t] = 0.f; }
  float acc[16] = {};
  int ntiles = bi + 1;
  for (int jt = 0; jt < ntiles; jt++) {
    __syncthreads();
#pragma unroll
    for (int i = 0; i < 4; i++) {  // load K,V tiles
      int lin = i * 256 + t;
      int row = lin >> 4, col = (lin & 15) * 4;
      size_t goff = ((size_t)(b * NN) + jt * 64 + row) * DD + h * DHH + col;
      *(float4*)&ks[row][col] = *(const float4*)(k + goff);
      *(float4*)&vs[row][col] = *(const float4*)(v + goff);
    }
    __syncthreads();
    {  // phase1: scores row r, cols w*16..+15
      float s[16] = {};
#pragma unroll
      for (int d4 = 0; d4 < 64; d4 += 4) {
#pragma unroll
        for (int j = 0; j < 16; j++) {
          float4 k4 = *(const float4*)&ks[w * 16 + j][d4];
          s[j] += qreg[d4] * k4.x + qreg[d4 + 1] * k4.y +
                  qreg[d4 + 2] * k4.z + qreg[d4 + 3] * k4.w;
        }
      }
#pragma unroll
      for (int j = 0; j < 16; j++) sc[r][w * 16 + j] = s[j];
    }
    __syncthreads();
    {  // online softmax: wave w owns rows w*16..+15
      int lane = t & 63;
      for (int rr = w * 16; rr < w * 16 + 16; rr++) {
        int ig = i0 + rr;
        int jg = jt * 64 + lane;
        float s = sc[rr][lane];
        if (jg > ig) s = -INFINITY;
        float m_old = marr[rr];
        float tm = s;
#pragma unroll
        for (int m = 32; m; m >>= 1) tm = fmaxf(tm, __shfl_xor(tm, m, 64));
        float m_new = fmaxf(m_old, tm);
        float p = __expf(s - m_new);
        float ts = p;
#pragma unroll
        for (int m = 32; m; m >>= 1) ts += __shfl_xor(ts, m, 64);
        float alpha = __expf(m_old - m_new);
        sc[rr][lane] = p;
        if (lane == 0) {
          marr[rr] = m_new; larr[rr] = larr[rr] * alpha + ts; aarr[rr] = alpha;
        }
      }
    }
    __syncthreads();
    {  // phase2: acc[r][w*16..+15] += P @ V
      float al = aarr[r];
#pragma unroll
      for (int dd = 0; dd < 16; dd++) acc[dd] *= al;
      for (int j = 0; j < 64; j++) {
        float p = sc[r][j];
        const float* vrow = &vs[j][w * 16];
#pragma unroll
        for (int dd = 0; dd < 16; dd += 4) {
          float4 v4 = *(const float4*)(vrow + dd);
          acc[dd] += p * v4.x; acc[dd + 1] += p * v4.y;
          acc[dd + 2] += p * v4.z; acc[dd + 3] += p * v4.w;
        }
      }
    }
  }
  if (knn) {
    __syncthreads();
    {  // memory logits (already scaled in topk kernel)
      int lane = t & 63;
      size_t rowbase = ((size_t)b * HH + h) * NN + i0;
      for (int rr = w * 16; rr < w * 16 + 16; rr++) {
        float s = (lane < TOPKK) ? topv[(rowbase + rr) * TOPKK + lane] : -INFINITY;
        float m_old = marr[rr];
        float tm = s;
#pragma unroll
        for (int m = 32; m; m >>= 1) tm = fmaxf(tm, __shfl_xor(tm, m, 64));
        float m_new = fmaxf(m_old, tm);
        float p = __expf(s - m_new);
        float ts = p;
#pragma unroll
        for (int m = 32; m; m >>= 1) ts += __shfl_xor(ts, m, 64);
        float alpha = __expf(m_old - m_new);
        sc[rr][lane] = p;
        if (lane < TOPKK) pidx[rr][lane] = topi[(rowbase + rr) * TOPKK + lane];
        if (lane == 0) {
          marr[rr] = m_new; larr[rr] = larr[rr] * alpha + ts; aarr[rr] = alpha;
        }
      }
    }
    __syncthreads();
    {
      float al = aarr[r];
#pragma unroll
      for (int dd = 0; dd < 16; dd++) acc[dd] *= al;
      const float* mvb = mem_v + (size_t)b * MEMM * DHH;
      for (int kk = 0; kk < TOPKK; kk++) {
        float p = sc[r][kk];
        const float* mrow = mvb + (size_t)pidx[r][kk] * DHH + w * 16;
#pragma unroll
        for (int dd = 0; dd < 16; dd += 4) {
          float4 m4 = *(const float4*)(mrow + dd);
          acc[dd] += p * m4.x; acc[dd + 1] += p * m4.y;
          acc[dd + 2] += p * m4.z; acc[dd + 3] += p * m4.w;
        }
      }
    }
  }
  {  // epilogue: out = acc / l
    float linv = 1.0f / larr[r];
    float* aop = ao + ((size_t)(b * NN) + iglob) * DD + h * DHH + w * 16;
#pragma unroll
    for (int dd = 0; dd < 16; dd += 4) {
      float4 o;
      o.x = acc[dd] * linv; o.y = acc[dd + 1] * linv;
      o.z = acc[dd + 2] * linv; o.w = acc[dd + 3] * linv;
      *(float4*)(aop + dd) = o;
    }
  }
}

// ---------------- host ----------------
extern "C" void kernel_launch(void* const* d_in, const int* in_sizes, int n_in,
                              void* d_out, int out_size, void* d_ws, size_t ws_size,
                              hipStream_t stream) {
  const float* x_in  = (const float*)d_in[0];
  const float* Wq    = (const float*)d_in[1];
  const float* Wk    = (const float*)d_in[2];
  const float* Wv    = (const float*)d_in[3];
  const float* Wo    = (const float*)d_in[4];
  const float* ln1_s = (const float*)d_in[5];
  const float* ln1_b = (const float*)d_in[6];
  const float* ln2_s = (const float*)d_in[7];
  const float* ln2_b = (const float*)d_in[8];
  const float* W1    = (const float*)d_in[9];
  const float* W2    = (const float*)d_in[10];
  const float* lnf_s = (const float*)d_in[11];
  const float* lnf_b = (const float*)d_in[12];
  const float* mem_k = (const float*)d_in[13];
  const float* mem_v = (const float*)d_in[14];

  // workspace layout (floats), total 14,680,064 floats = 58.72 MB:
  //  xb   [0        .. 2097152)   residual stream
  //  hb   [2097152  .. 4194304)   LN output
  //  qb/kb/vb/aob [4194304 .. 12582912)  (ffb 32MB aliases these during FFN)
  //  tvb  [12582912 .. 13631488)  top-k values  (B*H*N*TOPK = 1M elems)
  //  tib  [13631488 .. 14680064)  top-k indices (1M elems)
  float* ws  = (float*)d_ws;
  float* xb  = ws;
  float* hb  = ws + 2097152;
  float* qb  = ws + 4194304;
  float* kb  = ws + 6291456;
  float* vb  = ws + 8388608;
  float* aob = ws + 10485760;
  float* ffb = ws + 4194304;           // aliases qb..aob
  float* tvb = ws + 12582912;
  int*   tib = (int*)(ws + 13631488);

  dim3 blk(256);
  const size_t DD2 = (size_t)DD * DD;
  for (int l = 0; l < DEPTHH; l++) {
    const float* xcur = (l == 0) ? x_in : xb;
    ln_kernel<<<NT, blk, 0, stream>>>(xcur, ln1_s + l * DD, ln1_b + l * DD, hb);
    gemm_kernel<0><<<dim3(8, 64), blk, 0, stream>>>(hb, Wq + l * DD2, nullptr, qb, NT, DD, DD);
    gemm_kernel<0><<<dim3(8, 64), blk, 0, stream>>>(hb, Wk + l * DD2, nullptr, kb, NT, DD, DD);
    gemm_kernel<0><<<dim3(8, 64), blk, 0, stream>>>(hb, Wv + l * DD2, nullptr, vb, NT, DD, DD);
    int mi = (l == 3) ? 0 : ((l == 4) ? 1 : -1);
    if (mi >= 0)
      knn_topk_kernel<<<dim3(16, 8, 8), blk, 0, stream>>>(
          qb, mem_k + (size_t)mi * BB * MEMM * DHH, tvb, tib);
    attn_kernel<<<dim3(8, 8, 8), blk, 0, stream>>>(
        qb, kb, vb, aob, tvb, tib,
        mem_v + (size_t)(mi < 0 ? 0 : mi) * BB * MEMM * DHH, mi >= 0 ? 1 : 0);
    gemm_kernel<2><<<dim3(8, 64), blk, 0, stream>>>(aob, Wo + l * DD2, xcur, xb, NT, DD, DD);
    ln_kernel<<<NT, blk, 0, stream>>>(xb, ln2_s + l * DD, ln2_b + l * DD, hb);
    gemm_kernel<1><<<dim3(32, 64), blk, 0, stream>>>(
        hb, W1 + (size_t)l * DD * FFF, nullptr, ffb, NT, FFF, DD);
    gemm_kernel<2><<<dim3(8, 64), blk, 0, stream>>>(
        ffb, W2 + (size_t)l * FFF * DD, xb, xb, NT, DD, FFF);
  }
  ln_kernel<<<NT, blk, 0, stream>>>(xb, lnf_s, lnf_b, (float*)d_out);
}

// Round 6
// 6877.755 us; speedup vs baseline: 2.6300x; 1.2607x over previous
//
#include <hip/hip_runtime.h>
#include <math.h>

#define BB 8
#define NN 512
#define DD 512
#define HH 8
#define DHH 64
#define FFF 2048
#define MEMM 4096
#define TOPKK 32
#define DEPTHH 6
#define NT (BB*NN)   /* 4096 tokens */

typedef __bf16 bf16x8 __attribute__((ext_vector_type(8)));
typedef float f32x4 __attribute__((ext_vector_type(4)));

// ---------------- LayerNorm (fp32 in, fp32 or bf16 out) ----------------
template <int OBF16>
__global__ __launch_bounds__(256) void ln_kernel(const float* __restrict__ xin,
                                                 const float* __restrict__ g,
                                                 const float* __restrict__ bt,
                                                 void* __restrict__ outv) {
  __shared__ float red[4];
  int tok = blockIdx.x;
  const float* xr = xin + (size_t)tok * DD;
  int t = threadIdx.x;
  float v0 = xr[t], v1 = xr[t + 256];
  float s = v0 + v1;
#pragma unroll
  for (int m = 32; m; m >>= 1) s += __shfl_xor(s, m, 64);
  if ((t & 63) == 0) red[t >> 6] = s;
  __syncthreads();
  float mean = (red[0] + red[1] + red[2] + red[3]) * (1.0f / 512.0f);
  float d0 = v0 - mean, d1 = v1 - mean;
  float vv = d0 * d0 + d1 * d1;
#pragma unroll
  for (int m = 32; m; m >>= 1) vv += __shfl_xor(vv, m, 64);
  __syncthreads();
  if ((t & 63) == 0) red[t >> 6] = vv;
  __syncthreads();
  float var = (red[0] + red[1] + red[2] + red[3]) * (1.0f / 512.0f);
  float inv = rsqrtf(var + 1e-5f);
  float o0 = d0 * inv * g[t] + bt[t];
  float o1 = d1 * inv * g[t + 256] + bt[t + 256];
  if (OBF16) {
    __bf16* out = (__bf16*)outv;
    out[(size_t)tok * DD + t] = (__bf16)o0;
    out[(size_t)tok * DD + t + 256] = (__bf16)o1;
  } else {
    float* out = (float*)outv;
    out[(size_t)tok * DD + t] = o0;
    out[(size_t)tok * DD + t + 256] = o1;
  }
}

__device__ inline float gelu_f(float x) {
  float x3 = x * x * x;
  return 0.5f * x * (1.0f + tanhf(0.7978845608028654f * (x + 0.044715f * x3)));
}

// ------------- weight transpose+convert: src[K][N] f32 -> dst[N][K] bf16 ----
__global__ __launch_bounds__(256) void transpose_bf16_kernel(const float* __restrict__ src,
                                                             __bf16* __restrict__ dst,
                                                             int K, int N) {
  __shared__ float tile[32][33];
  int n0 = blockIdx.x * 32, k0 = blockIdx.y * 32;
  int tx = threadIdx.x & 31, ty = threadIdx.x >> 5;
#pragma unroll
  for (int i = 0; i < 4; i++) {
    int r = ty + i * 8;
    tile[r][tx] = src[(size_t)(k0 + r) * N + n0 + tx];
  }
  __syncthreads();
#pragma unroll
  for (int i = 0; i < 4; i++) {
    int r = ty + i * 8;
    dst[(size_t)(n0 + r) * K + k0 + tx] = (__bf16)tile[tx][r];
  }
}

// ---------------- bf16 MFMA GEMM: C = A(MxK) @ Bt(NxK)^T --------------------
// A row-major bf16, Bt row-major bf16 (i.e. B transposed). 128x64 tile, BK=64.
// 4 waves in 2x2; each wave 64x32 = 4x2 MFMA 16x16x32 tiles.
// EPI: 0 none, 1 gelu, 2 +R(f32). OBF16: output dtype.
template <int EPI, int OBF16>
__global__ __launch_bounds__(256) void gemm_mfma(const __bf16* __restrict__ A,
                                                 const __bf16* __restrict__ Bt,
                                                 const float* __restrict__ R,
                                                 void* __restrict__ Cout,
                                                 int M, int N, int K) {
  __shared__ __bf16 Als[128 * 72];   // rows padded to 72 (2-way max conflict)
  __shared__ __bf16 Bls[64 * 72];
  int t = threadIdx.x;
  int bn = blockIdx.x, bm = blockIdx.y;
  int lane = t & 63, wave = t >> 6;
  int wr = wave >> 1, wc = wave & 1;
  int m15 = lane & 15, q = lane >> 4;
  f32x4 acc[4][2] = {};
  for (int kt = 0; kt < K; kt += 64) {
    __syncthreads();
#pragma unroll
    for (int i = 0; i < 4; i++) {  // stage A 128x64
      int c = t + i * 256;
      int row = c >> 3, pb = c & 7;
      *(uint4*)&Als[row * 72 + pb * 8] =
          *(const uint4*)(A + (size_t)(bm * 128 + row) * K + kt + pb * 8);
    }
#pragma unroll
    for (int i = 0; i < 2; i++) {  // stage Bt 64x64
      int c = t + i * 256;
      int row = c >> 3, pb = c & 7;
      *(uint4*)&Bls[row * 72 + pb * 8] =
          *(const uint4*)(Bt + (size_t)(bn * 64 + row) * K + kt + pb * 8);
    }
    __syncthreads();
#pragma unroll
    for (int ks = 0; ks < 2; ks++) {
      bf16x8 af[4], bf[2];
#pragma unroll
      for (int mt = 0; mt < 4; mt++)
        af[mt] = *(const bf16x8*)&Als[(wr * 64 + mt * 16 + m15) * 72 + (ks * 4 + q) * 8];
#pragma unroll
      for (int nt = 0; nt < 2; nt++)
        bf[nt] = *(const bf16x8*)&Bls[(wc * 32 + nt * 16 + m15) * 72 + (ks * 4 + q) * 8];
#pragma unroll
      for (int mt = 0; mt < 4; mt++)
#pragma unroll
        for (int nt = 0; nt < 2; nt++)
          acc[mt][nt] = __builtin_amdgcn_mfma_f32_16x16x32_bf16(af[mt], bf[nt],
                                                                acc[mt][nt], 0, 0, 0);
    }
  }
  // epilogue: C/D layout col=lane&15, row=(lane>>4)*4+reg
#pragma unroll
  for (int mt = 0; mt < 4; mt++) {
#pragma unroll
    for (int nt = 0; nt < 2; nt++) {
      int gc = bn * 64 + wc * 32 + nt * 16 + m15;
#pragma unroll
      for (int r = 0; r < 4; r++) {
        int gr = bm * 128 + wr * 64 + mt * 16 + q * 4 + r;
        size_t off = (size_t)gr * N + gc;
        float v = acc[mt][nt][r];
        if (EPI == 1) v = gelu_f(v);
        if (EPI == 2) v += R[off];
        if (OBF16) ((__bf16*)Cout)[off] = (__bf16)v;
        else       ((float*)Cout)[off] = v;
      }
    }
  }
}

// ---------------- fused q@mem_k + top-32 (register-resident) ----------------
__device__ __forceinline__ void insert32vi(float (&rtv)[32], int (&rti)[32],
                                           float sv, int idx, float& thr) {
  float mv = rtv[0], mv2 = INFINITY;
  int mi = 0;
#pragma unroll
  for (int k = 1; k < 32; k++) {
    float v = rtv[k];
    bool lt = v < mv;
    mv2 = lt ? mv : fminf(mv2, v);
    mv = lt ? v : mv;
    mi = lt ? k : mi;
  }
#pragma unroll
  for (int k = 0; k < 32; k++) {
    bool hit = (k == mi);
    rtv[k] = hit ? sv : rtv[k];
    rti[k] = hit ? idx : rti[k];
  }
  thr = fminf(mv2, sv);
}

__global__ __launch_bounds__(256) void knn_topk_kernel(const float* __restrict__ q,
                                                       const float* __restrict__ mem_k,
                                                       float* __restrict__ topv,
                                                       int* __restrict__ topi) {
  __shared__ float qs[32][68];
  __shared__ float ks[128][68];
  __shared__ unsigned short midx[32 * 260];
  __shared__ float rthr[8][32];
  int it = blockIdx.x, h = blockIdx.y, b = blockIdx.z;
  int t = threadIdx.x;
  const float scale = 0.125f;
  {
    int row = t >> 3;
    int col = (t & 7) * 8;
    const float* qp = q + ((size_t)(b * NN) + it * 32 + row) * DD + h * DHH + col;
    *(float4*)&qs[row][col]     = *(const float4*)qp;
    *(float4*)&qs[row][col + 4] = *(const float4*)(qp + 4);
  }
  int tx = t & 15, ty = t >> 4;
  int r = t & 31, p = t >> 5;
  rthr[p][r] = -INFINITY;
  float rtv[32]; int rti[32];
#pragma unroll
  for (int k = 0; k < 32; k++) { rtv[k] = -INFINITY; rti[k] = 0; }
  float thr = -INFINITY;
  float* scb = &ks[0][0];
  const float* kbase = mem_k + (size_t)b * MEMM * DHH;

  for (int mt = 0; mt < MEMM; mt += 128) {
    __syncthreads();
    {
      const float* kp = kbase + (size_t)mt * DHH;
#pragma unroll
      for (int i = 0; i < 8; i++) {
        int lin = i * 256 + t;
        int row = lin >> 4, col = (lin & 15) * 4;
        *(float4*)&ks[row][col] = *(const float4*)(kp + (size_t)row * DHH + col);
      }
    }
    __syncthreads();
    float acc[2][8] = {};
#pragma unroll 4
    for (int d4 = 0; d4 < 64; d4 += 4) {
      float4 a0 = *(const float4*)&qs[2 * ty][d4];
      float4 a1 = *(const float4*)&qs[2 * ty + 1][d4];
#pragma unroll
      for (int j = 0; j < 8; j++) {
        float4 bv = *(const float4*)&ks[tx + 16 * j][d4];
        acc[0][j] += a0.x * bv.x + a0.y * bv.y + a0.z * bv.z + a0.w * bv.w;
        acc[1][j] += a1.x * bv.x + a1.y * bv.y + a1.z * bv.z + a1.w * bv.w;
      }
    }
    __syncthreads();
#pragma unroll
    for (int i2 = 0; i2 < 2; i2++)
#pragma unroll
      for (int j = 0; j < 8; j++)
        scb[(size_t)(2 * ty + i2) * 132 + tx + 16 * j] = acc[i2][j] * scale;
    __syncthreads();
    {
      float B2 = rthr[0][r];
#pragma unroll
      for (int j = 1; j < 8; j++) B2 = fmaxf(B2, rthr[j][r]);
      const float* srow = scb + (size_t)132 * r + 16 * p;
#pragma unroll 1
      for (int c = 0; c < 16; c++) {
        int cc = (c + r) & 15;
        float sv = srow[cc];
        if (sv > fmaxf(thr, B2))
          insert32vi(rtv, rti, sv, mt + 16 * p + cc, thr);
      }
      rthr[p][r] = thr;
    }
  }
  __syncthreads();
  {
    float* mvals = &ks[0][0];
#pragma unroll
    for (int k = 0; k < 32; k++) {
      int cc = (k + r) & 31;
      mvals[(size_t)260 * r + 32 * p + cc] = rtv[k];
      midx[(size_t)260 * r + 32 * p + cc] = (unsigned short)rti[k];
    }
  }
  __syncthreads();
  if (t < 32) {
    const float* mvals = &ks[0][0];
#pragma unroll 1
    for (int c = 0; c < 224; c++) {
      int cc = c + r; if (cc >= 224) cc -= 224;
      float sv = mvals[(size_t)260 * r + 32 + cc];
      if (sv > thr)
        insert32vi(rtv, rti, sv, (int)midx[(size_t)260 * r + 32 + cc], thr);
    }
    size_t rowg = ((size_t)b * HH + h) * NN + it * 32 + r;
#pragma unroll
    for (int k = 0; k < 32; k++) {
      topv[rowg * TOPKK + k] = rtv[k];
      topi[rowg * TOPKK + k] = rti[k];
    }
  }
}

// ---------------- flash attention (+ optional kNN memory logits) ----------
// grid (N/64, H, B), block 256. ao (bf16) layout [b][i][h*64+d]
__global__ __launch_bounds__(256) void attn_kernel(const float* __restrict__ q,
                                                   const float* __restrict__ k,
                                                   const float* __restrict__ v,
                                                   __bf16* __restrict__ ao,
                                                   const float* __restrict__ topv,
                                                   const int* __restrict__ topi,
                                                   const float* __restrict__ mem_v,
                                                   int knn) {
  int bi = blockIdx.x, h = blockIdx.y, b = blockIdx.z;
  __shared__ float ks[64][64];
  __shared__ float vs[64][64];
  __shared__ float sc[64][65];
  __shared__ float marr[64], larr[64], aarr[64];
  __shared__ int pidx[64][33];
  const float scale = 0.125f;
  int t = threadIdx.x;
  int r = t & 63;
  int w = t >> 6;
  int i0 = bi * 64;
  int iglob = i0 + r;

  float qreg[64];
  {
    const float* qp = q + ((size_t)(b * NN) + iglob) * DD + h * DHH;
#pragma unroll
    for (int d4 = 0; d4 < 64; d4 += 4) {
      float4 a = *(const float4*)(qp + d4);
      qreg[d4] = a.x * scale; qreg[d4 + 1] = a.y * scale;
      qreg[d4 + 2] = a.z * scale; qreg[d4 + 3] = a.w * scale;
    }
  }
  if (t < 64) { marr[t] = -INFINITY; larr[t] = 0.f; }
  float acc[16] = {};
  int ntiles = bi + 1;
  for (int jt = 0; jt < ntiles; jt++) {
    __syncthreads();
#pragma unroll
    for (int i = 0; i < 4; i++) {
      int lin = i * 256 + t;
      int row = lin >> 4, col = (lin & 15) * 4;
      size_t goff = ((size_t)(b * NN) + jt * 64 + row) * DD + h * DHH + col;
      *(float4*)&ks[row][col] = *(const float4*)(k + goff);
      *(float4*)&vs[row][col] = *(const float4*)(v + goff);
    }
    __syncthreads();
    {
      float s[16] = {};
#pragma unroll
      for (int d4 = 0; d4 < 64; d4 += 4) {
#pragma unroll
        for (int j = 0; j < 16; j++) {
          float4 k4 = *(const float4*)&ks[w * 16 + j][d4];
          s[j] += qreg[d4] * k4.x + qreg[d4 + 1] * k4.y +
                  qreg[d4 + 2] * k4.z + qreg[d4 + 3] * k4.w;
        }
      }
#pragma unroll
      for (int j = 0; j < 16; j++) sc[r][w * 16 + j] = s[j];
    }
    __syncthreads();
    {
      int lane = t & 63;
      for (int rr = w * 16; rr < w * 16 + 16; rr++) {
        int ig = i0 + rr;
        int jg = jt * 64 + lane;
        float s = sc[rr][lane];
        if (jg > ig) s = -INFINITY;
        float m_old = marr[rr];
        float tm = s;
#pragma unroll
        for (int m = 32; m; m >>= 1) tm = fmaxf(tm, __shfl_xor(tm, m, 64));
        float m_new = fmaxf(m_old, tm);
        float p = __expf(s - m_new);
        float ts = p;
#pragma unroll
        for (int m = 32; m; m >>= 1) ts += __shfl_xor(ts, m, 64);
        float alpha = __expf(m_old - m_new);
        sc[rr][lane] = p;
        if (lane == 0) {
          marr[rr] = m_new; larr[rr] = larr[rr] * alpha + ts; aarr[rr] = alpha;
        }
      }
    }
    __syncthreads();
    {
      float al = aarr[r];
#pragma unroll
      for (int dd = 0; dd < 16; dd++) acc[dd] *= al;
      for (int j = 0; j < 64; j++) {
        float p = sc[r][j];
        const float* vrow = &vs[j][w * 16];
#pragma unroll
        for (int dd = 0; dd < 16; dd += 4) {
          float4 v4 = *(const float4*)(vrow + dd);
          acc[dd] += p * v4.x; acc[dd + 1] += p * v4.y;
          acc[dd + 2] += p * v4.z; acc[dd + 3] += p * v4.w;
        }
      }
    }
  }
  if (knn) {
    __syncthreads();
    {
      int lane = t & 63;
      size_t rowbase = ((size_t)b * HH + h) * NN + i0;
      for (int rr = w * 16; rr < w * 16 + 16; rr++) {
        float s = (lane < TOPKK) ? topv[(rowbase + rr) * TOPKK + lane] : -INFINITY;
        float m_old = marr[rr];
        float tm = s;
#pragma unroll
        for (int m = 32; m; m >>= 1) tm = fmaxf(tm, __shfl_xor(tm, m, 64));
        float m_new = fmaxf(m_old, tm);
        float p = __expf(s - m_new);
        float ts = p;
#pragma unroll
        for (int m = 32; m; m >>= 1) ts += __shfl_xor(ts, m, 64);
        float alpha = __expf(m_old - m_new);
        sc[rr][lane] = p;
        if (lane < TOPKK) pidx[rr][lane] = topi[(rowbase + rr) * TOPKK + lane];
        if (lane == 0) {
          marr[rr] = m_new; larr[rr] = larr[rr] * alpha + ts; aarr[rr] = alpha;
        }
      }
    }
    __syncthreads();
    {
      float al = aarr[r];
#pragma unroll
      for (int dd = 0; dd < 16; dd++) acc[dd] *= al;
      const float* mvb = mem_v + (size_t)b * MEMM * DHH;
      for (int kk = 0; kk < TOPKK; kk++) {
        float p = sc[r][kk];
        const float* mrow = mvb + (size_t)pidx[r][kk] * DHH + w * 16;
#pragma unroll
        for (int dd = 0; dd < 16; dd += 4) {
          float4 m4 = *(const float4*)(mrow + dd);
          acc[dd] += p * m4.x; acc[dd + 1] += p * m4.y;
          acc[dd + 2] += p * m4.z; acc[dd + 3] += p * m4.w;
        }
      }
    }
  }
  {
    float linv = 1.0f / larr[r];
    __bf16* aop = ao + ((size_t)(b * NN) + iglob) * DD + h * DHH + w * 16;
#pragma unroll
    for (int dd = 0; dd < 16; dd++) aop[dd] = (__bf16)(acc[dd] * linv);
  }
}

// ---------------- host ----------------
extern "C" void kernel_launch(void* const* d_in, const int* in_sizes, int n_in,
                              void* d_out, int out_size, void* d_ws, size_t ws_size,
                              hipStream_t stream) {
  const float* x_in  = (const float*)d_in[0];
  const float* Wq    = (const float*)d_in[1];
  const float* Wk    = (const float*)d_in[2];
  const float* Wv    = (const float*)d_in[3];
  const float* Wo    = (const float*)d_in[4];
  const float* ln1_s = (const float*)d_in[5];
  const float* ln1_b = (const float*)d_in[6];
  const float* ln2_s = (const float*)d_in[7];
  const float* ln2_b = (const float*)d_in[8];
  const float* W1    = (const float*)d_in[9];
  const float* W2    = (const float*)d_in[10];
  const float* lnf_s = (const float*)d_in[11];
  const float* lnf_b = (const float*)d_in[12];
  const float* mem_k = (const float*)d_in[13];
  const float* mem_v = (const float*)d_in[14];

  // workspace layout (float offsets), total 14,155,776 floats = 56.6 MB:
  float* ws  = (float*)d_ws;
  float*  xb    = ws;                            // 2M f32 residual
  float*  qb    = ws + 2097152;                  // 2M f32
  float*  kb    = ws + 4194304;                  // 2M f32
  float*  vb    = ws + 6291456;                  // 2M f32
  __bf16* hb16  = (__bf16*)(ws + 8388608);       // 2M bf16 (LN out)
  __bf16* ao16  = (__bf16*)(ws + 9437184);       // 2M bf16 (attn out)
  __bf16* wqT   = (__bf16*)(ws + 10485760);      // 512x512 bf16
  __bf16* wkT   = (__bf16*)(ws + 10616832);
  __bf16* wvT   = (__bf16*)(ws + 10747904);
  __bf16* woT   = (__bf16*)(ws + 10878976);
  __bf16* w1T   = (__bf16*)(ws + 11010048);      // 2048x512 bf16
  __bf16* w2T   = (__bf16*)(ws + 11534336);      // 512x2048 bf16
  float*  tvb   = ws + 12058624;                 // 1M f32
  int*    tib   = (int*)(ws + 13107200);         // 1M i32
  __bf16* ffb16 = (__bf16*)(ws + 2097152);       // 8M bf16, aliases qb+kb (dead in FFN)

  dim3 blk(256);
  const size_t DD2 = (size_t)DD * DD;
  for (int l = 0; l < DEPTHH; l++) {
    const float* xcur = (l == 0) ? x_in : xb;
    // weight convert+transpose for this layer
    transpose_bf16_kernel<<<dim3(16, 16), blk, 0, stream>>>(Wq + l * DD2, wqT, DD, DD);
    transpose_bf16_kernel<<<dim3(16, 16), blk, 0, stream>>>(Wk + l * DD2, wkT, DD, DD);
    transpose_bf16_kernel<<<dim3(16, 16), blk, 0, stream>>>(Wv + l * DD2, wvT, DD, DD);
    transpose_bf16_kernel<<<dim3(16, 16), blk, 0, stream>>>(Wo + l * DD2, woT, DD, DD);
    transpose_bf16_kernel<<<dim3(64, 16), blk, 0, stream>>>(W1 + (size_t)l * DD * FFF, w1T, DD, FFF);
    transpose_bf16_kernel<<<dim3(16, 64), blk, 0, stream>>>(W2 + (size_t)l * FFF * DD, w2T, FFF, DD);

    ln_kernel<1><<<NT, blk, 0, stream>>>(xcur, ln1_s + l * DD, ln1_b + l * DD, hb16);
    gemm_mfma<0, 0><<<dim3(8, 32), blk, 0, stream>>>(hb16, wqT, nullptr, qb, NT, DD, DD);
    gemm_mfma<0, 0><<<dim3(8, 32), blk, 0, stream>>>(hb16, wkT, nullptr, kb, NT, DD, DD);
    gemm_mfma<0, 0><<<dim3(8, 32), blk, 0, stream>>>(hb16, wvT, nullptr, vb, NT, DD, DD);
    int mi = (l == 3) ? 0 : ((l == 4) ? 1 : -1);
    if (mi >= 0)
      knn_topk_kernel<<<dim3(16, 8, 8), blk, 0, stream>>>(
          qb, mem_k + (size_t)mi * BB * MEMM * DHH, tvb, tib);
    attn_kernel<<<dim3(8, 8, 8), blk, 0, stream>>>(
        qb, kb, vb, ao16, tvb, tib,
        mem_v + (size_t)(mi < 0 ? 0 : mi) * BB * MEMM * DHH, mi >= 0 ? 1 : 0);
    gemm_mfma<2, 0><<<dim3(8, 32), blk, 0, stream>>>(ao16, woT, xcur, xb, NT, DD, DD);
    ln_kernel<1><<<NT, blk, 0, stream>>>(xb, ln2_s + l * DD, ln2_b + l * DD, hb16);
    gemm_mfma<1, 1><<<dim3(32, 32), blk, 0, stream>>>(hb16, w1T, nullptr, ffb16, NT, FFF, DD);
    gemm_mfma<2, 0><<<dim3(8, 32), blk, 0, stream>>>(ffb16, w2T, xb, xb, NT, DD, FFF);
  }
  ln_kernel<0><<<NT, blk, 0, stream>>>(xb, lnf_s, lnf_b, (float*)d_out);
}

// Round 7
// 6875.777 us; speedup vs baseline: 2.6307x; 1.0003x over previous
//
#include <hip/hip_runtime.h>
#include <math.h>

#define BB 8
#define NN 512
#define DD 512
#define HH 8
#define DHH 64
#define FFF 2048
#define MEMM 4096
#define TOPKK 32
#define DEPTHH 6
#define NT (BB*NN)   /* 4096 tokens */

typedef __bf16 bf16x8 __attribute__((ext_vector_type(8)));
typedef float f32x4 __attribute__((ext_vector_type(4)));

// ---------------- LayerNorm (fp32 in, fp32 or bf16 out) ----------------
template <int OBF16>
__global__ __launch_bounds__(256) void ln_kernel(const float* __restrict__ xin,
                                                 const float* __restrict__ g,
                                                 const float* __restrict__ bt,
                                                 void* __restrict__ outv) {
  __shared__ float red[4];
  int tok = blockIdx.x;
  const float* xr = xin + (size_t)tok * DD;
  int t = threadIdx.x;
  float v0 = xr[t], v1 = xr[t + 256];
  float s = v0 + v1;
#pragma unroll
  for (int m = 32; m; m >>= 1) s += __shfl_xor(s, m, 64);
  if ((t & 63) == 0) red[t >> 6] = s;
  __syncthreads();
  float mean = (red[0] + red[1] + red[2] + red[3]) * (1.0f / 512.0f);
  float d0 = v0 - mean, d1 = v1 - mean;
  float vv = d0 * d0 + d1 * d1;
#pragma unroll
  for (int m = 32; m; m >>= 1) vv += __shfl_xor(vv, m, 64);
  __syncthreads();
  if ((t & 63) == 0) red[t >> 6] = vv;
  __syncthreads();
  float var = (red[0] + red[1] + red[2] + red[3]) * (1.0f / 512.0f);
  float inv = rsqrtf(var + 1e-5f);
  float o0 = d0 * inv * g[t] + bt[t];
  float o1 = d1 * inv * g[t + 256] + bt[t + 256];
  if (OBF16) {
    __bf16* out = (__bf16*)outv;
    out[(size_t)tok * DD + t] = (__bf16)o0;
    out[(size_t)tok * DD + t + 256] = (__bf16)o1;
  } else {
    float* out = (float*)outv;
    out[(size_t)tok * DD + t] = o0;
    out[(size_t)tok * DD + t + 256] = o1;
  }
}

__device__ inline float gelu_f(float x) {
  float x3 = x * x * x;
  return 0.5f * x * (1.0f + tanhf(0.7978845608028654f * (x + 0.044715f * x3)));
}

// ------------- weight transpose+convert: src[K][N] f32 -> dst[N][K] bf16 ----
__global__ __launch_bounds__(256) void transpose_bf16_kernel(const float* __restrict__ src,
                                                             __bf16* __restrict__ dst,
                                                             int K, int N) {
  __shared__ float tile[32][33];
  int n0 = blockIdx.x * 32, k0 = blockIdx.y * 32;
  int tx = threadIdx.x & 31, ty = threadIdx.x >> 5;
#pragma unroll
  for (int i = 0; i < 4; i++) {
    int r = ty + i * 8;
    tile[r][tx] = src[(size_t)(k0 + r) * N + n0 + tx];
  }
  __syncthreads();
#pragma unroll
  for (int i = 0; i < 4; i++) {
    int r = ty + i * 8;
    dst[(size_t)(n0 + r) * K + k0 + tx] = (__bf16)tile[tx][r];
  }
}

// ---------------- bf16 MFMA GEMM: C = A(MxK) @ Bt(NxK)^T --------------------
template <int EPI, int OBF16>
__global__ __launch_bounds__(256) void gemm_mfma(const __bf16* __restrict__ A,
                                                 const __bf16* __restrict__ Bt,
                                                 const float* __restrict__ R,
                                                 void* __restrict__ Cout,
                                                 int M, int N, int K) {
  __shared__ __bf16 Als[128 * 72];
  __shared__ __bf16 Bls[64 * 72];
  int t = threadIdx.x;
  int bn = blockIdx.x, bm = blockIdx.y;
  int lane = t & 63, wave = t >> 6;
  int wr = wave >> 1, wc = wave & 1;
  int m15 = lane & 15, q = lane >> 4;
  f32x4 acc[4][2] = {};
  for (int kt = 0; kt < K; kt += 64) {
    __syncthreads();
#pragma unroll
    for (int i = 0; i < 4; i++) {
      int c = t + i * 256;
      int row = c >> 3, pb = c & 7;
      *(uint4*)&Als[row * 72 + pb * 8] =
          *(const uint4*)(A + (size_t)(bm * 128 + row) * K + kt + pb * 8);
    }
#pragma unroll
    for (int i = 0; i < 2; i++) {
      int c = t + i * 256;
      int row = c >> 3, pb = c & 7;
      *(uint4*)&Bls[row * 72 + pb * 8] =
          *(const uint4*)(Bt + (size_t)(bn * 64 + row) * K + kt + pb * 8);
    }
    __syncthreads();
#pragma unroll
    for (int ks = 0; ks < 2; ks++) {
      bf16x8 af[4], bf[2];
#pragma unroll
      for (int mt = 0; mt < 4; mt++)
        af[mt] = *(const bf16x8*)&Als[(wr * 64 + mt * 16 + m15) * 72 + (ks * 4 + q) * 8];
#pragma unroll
      for (int nt = 0; nt < 2; nt++)
        bf[nt] = *(const bf16x8*)&Bls[(wc * 32 + nt * 16 + m15) * 72 + (ks * 4 + q) * 8];
#pragma unroll
      for (int mt = 0; mt < 4; mt++)
#pragma unroll
        for (int nt = 0; nt < 2; nt++)
          acc[mt][nt] = __builtin_amdgcn_mfma_f32_16x16x32_bf16(af[mt], bf[nt],
                                                                acc[mt][nt], 0, 0, 0);
    }
  }
#pragma unroll
  for (int mt = 0; mt < 4; mt++) {
#pragma unroll
    for (int nt = 0; nt < 2; nt++) {
      int gc = bn * 64 + wc * 32 + nt * 16 + m15;
#pragma unroll
      for (int r = 0; r < 4; r++) {
        int gr = bm * 128 + wr * 64 + mt * 16 + q * 4 + r;
        size_t off = (size_t)gr * N + gc;
        float v = acc[mt][nt][r];
        if (EPI == 1) v = gelu_f(v);
        if (EPI == 2) v += R[off];
        if (OBF16) ((__bf16*)Cout)[off] = (__bf16)v;
        else       ((float*)Cout)[off] = v;
      }
    }
  }
}

// ============ kNN path A: score GEMM -> S[b][h][i][m] (fp32, global) ========
// grid (N/32, H, B), block 256. 32 rows x 128-cand tiles, 2x8 microtile.
__global__ __launch_bounds__(256) void knn_score_kernel(const float* __restrict__ q,
                                                        const float* __restrict__ mem_k,
                                                        float* __restrict__ S) {
  __shared__ float qs[32][68];
  __shared__ float ks[128][68];
  __shared__ float scb[32][132];
  int it = blockIdx.x, h = blockIdx.y, b = blockIdx.z;
  int t = threadIdx.x;
  const float scale = 0.125f;
  {
    int row = t >> 3;
    int col = (t & 7) * 8;
    const float* qp = q + ((size_t)(b * NN) + it * 32 + row) * DD + h * DHH + col;
    *(float4*)&qs[row][col]     = *(const float4*)qp;
    *(float4*)&qs[row][col + 4] = *(const float4*)(qp + 4);
  }
  int tx = t & 15, ty = t >> 4;
  const float* kbase = mem_k + (size_t)b * MEMM * DHH;
  size_t srowbase = (((size_t)b * HH + h) * NN + it * 32) * MEMM;
  for (int mt = 0; mt < MEMM; mt += 128) {
    {  // stage mem_k tile 128x64 (coalesced)
      const float* kp = kbase + (size_t)mt * DHH;
#pragma unroll
      for (int i = 0; i < 8; i++) {
        int lin = i * 256 + t;
        int row = lin >> 4, col = (lin & 15) * 4;
        *(float4*)&ks[row][col] = *(const float4*)(kp + (size_t)row * DHH + col);
      }
    }
    __syncthreads();
    float acc[2][8] = {};
#pragma unroll 4
    for (int d4 = 0; d4 < 64; d4 += 4) {
      float4 a0 = *(const float4*)&qs[2 * ty][d4];
      float4 a1 = *(const float4*)&qs[2 * ty + 1][d4];
#pragma unroll
      for (int j = 0; j < 8; j++) {
        float4 bv = *(const float4*)&ks[tx + 16 * j][d4];
        acc[0][j] += a0.x * bv.x + a0.y * bv.y + a0.z * bv.z + a0.w * bv.w;
        acc[1][j] += a1.x * bv.x + a1.y * bv.y + a1.z * bv.z + a1.w * bv.w;
      }
    }
#pragma unroll
    for (int i2 = 0; i2 < 2; i2++)
#pragma unroll
      for (int j = 0; j < 8; j++)
        scb[2 * ty + i2][tx + 16 * j] = acc[i2][j] * scale;
    __syncthreads();
    {  // coalesced dump scb -> S
      int row = t >> 3, cb = (t & 7) * 16;
      float* dst = S + srowbase + (size_t)row * MEMM + mt + cb;
#pragma unroll
      for (int c = 0; c < 16; c += 4)
        *(float4*)(dst + c) = *(const float4*)&scb[row][cb + c];
    }
    // next stage-ks write is ordered after this barrier region by the
    // __syncthreads at the top of the next iteration's GEMM (below)
    __syncthreads();
  }
}

// ============ kNN path B: exact top-32 per row via bit-serial radix =========
// one wave per row; 64 scores/lane in registers; no barriers, no divergence.
__global__ __launch_bounds__(256, 4) void knn_select_kernel(const float* __restrict__ S,
                                                            float* __restrict__ topv,
                                                            int* __restrict__ topi) {
  int lane = threadIdx.x & 63;
  int row = blockIdx.x * 4 + (threadIdx.x >> 6);
  const float* srow = S + (size_t)row * MEMM;
  unsigned u[64];
#pragma unroll
  for (int i = 0; i < 64; i++) {
    union { float f; unsigned b; } cv;
    cv.f = srow[i * 64 + lane];
    unsigned b = cv.b;
    u[i] = (b & 0x80000000u) ? ~b : (b | 0x80000000u);  // order-preserving map
  }
  unsigned T = 0;
#pragma unroll 1
  for (int bit = 31; bit >= 0; --bit) {
    unsigned Tp = T | (1u << bit);
    int c = 0;
#pragma unroll
    for (int i = 0; i < 64; i++) c += (u[i] >= Tp) ? 1 : 0;
#pragma unroll
    for (int m = 32; m; m >>= 1) c += __shfl_xor(c, m, 64);
    if (c >= TOPKK) T = Tp;
  }
  // T = exact 32nd-largest pattern. Emit strictly-greater, then ties.
  unsigned long long below = (1ull << lane) - 1ull;
  float* tvrow = topv + (size_t)row * TOPKK;
  int* tirow = topi + (size_t)row * TOPKK;
  int g = 0;
#pragma unroll
  for (int i = 0; i < 64; i++) {
    bool f = u[i] > T;
    unsigned long long m = __ballot(f);
    if (f) {
      int pos = g + __popcll(m & below);
      union { unsigned b; float f2; } rv;
      rv.b = (u[i] & 0x80000000u) ? (u[i] & 0x7fffffffu) : ~u[i];
      tvrow[pos] = rv.f2;
      tirow[pos] = i * 64 + lane;
    }
    g += __popcll(m);
  }
#pragma unroll
  for (int i = 0; i < 64; i++) {
    if (g < TOPKK) {  // wave-uniform
      bool f = (u[i] == T);
      unsigned long long m = __ballot(f);
      if (f) {
        int pos = g + __popcll(m & below);
        if (pos < TOPKK) {
          union { unsigned b; float f2; } rv;
          rv.b = (T & 0x80000000u) ? (T & 0x7fffffffu) : ~T;
          tvrow[pos] = rv.f2;
          tirow[pos] = i * 64 + lane;
        }
      }
      g += __popcll(m);
    }
  }
}

// ---------------- fused q@mem_k + top-32 (FALLBACK, small ws) ---------------
__device__ __forceinline__ void insert32vi(float (&rtv)[32], int (&rti)[32],
                                           float sv, int idx, float& thr) {
  float mv = rtv[0], mv2 = INFINITY;
  int mi = 0;
#pragma unroll
  for (int k = 1; k < 32; k++) {
    float v = rtv[k];
    bool lt = v < mv;
    mv2 = lt ? mv : fminf(mv2, v);
    mv = lt ? v : mv;
    mi = lt ? k : mi;
  }
#pragma unroll
  for (int k = 0; k < 32; k++) {
    bool hit = (k == mi);
    rtv[k] = hit ? sv : rtv[k];
    rti[k] = hit ? idx : rti[k];
  }
  thr = fminf(mv2, sv);
}

__global__ __launch_bounds__(256) void knn_topk_kernel(const float* __restrict__ q,
                                                       const float* __restrict__ mem_k,
                                                       float* __restrict__ topv,
                                                       int* __restrict__ topi) {
  __shared__ float qs[32][68];
  __shared__ float ks[128][68];
  __shared__ unsigned short midx[32 * 260];
  __shared__ float rthr[8][32];
  int it = blockIdx.x, h = blockIdx.y, b = blockIdx.z;
  int t = threadIdx.x;
  const float scale = 0.125f;
  {
    int row = t >> 3;
    int col = (t & 7) * 8;
    const float* qp = q + ((size_t)(b * NN) + it * 32 + row) * DD + h * DHH + col;
    *(float4*)&qs[row][col]     = *(const float4*)qp;
    *(float4*)&qs[row][col + 4] = *(const float4*)(qp + 4);
  }
  int tx = t & 15, ty = t >> 4;
  int r = t & 31, p = t >> 5;
  rthr[p][r] = -INFINITY;
  float rtv[32]; int rti[32];
#pragma unroll
  for (int k = 0; k < 32; k++) { rtv[k] = -INFINITY; rti[k] = 0; }
  float thr = -INFINITY;
  float* scb = &ks[0][0];
  const float* kbase = mem_k + (size_t)b * MEMM * DHH;

  for (int mt = 0; mt < MEMM; mt += 128) {
    __syncthreads();
    {
      const float* kp = kbase + (size_t)mt * DHH;
#pragma unroll
      for (int i = 0; i < 8; i++) {
        int lin = i * 256 + t;
        int row = lin >> 4, col = (lin & 15) * 4;
        *(float4*)&ks[row][col] = *(const float4*)(kp + (size_t)row * DHH + col);
      }
    }
    __syncthreads();
    float acc[2][8] = {};
#pragma unroll 4
    for (int d4 = 0; d4 < 64; d4 += 4) {
      float4 a0 = *(const float4*)&qs[2 * ty][d4];
      float4 a1 = *(const float4*)&qs[2 * ty + 1][d4];
#pragma unroll
      for (int j = 0; j < 8; j++) {
        float4 bv = *(const float4*)&ks[tx + 16 * j][d4];
        acc[0][j] += a0.x * bv.x + a0.y * bv.y + a0.z * bv.z + a0.w * bv.w;
        acc[1][j] += a1.x * bv.x + a1.y * bv.y + a1.z * bv.z + a1.w * bv.w;
      }
    }
    __syncthreads();
#pragma unroll
    for (int i2 = 0; i2 < 2; i2++)
#pragma unroll
      for (int j = 0; j < 8; j++)
        scb[(size_t)(2 * ty + i2) * 132 + tx + 16 * j] = acc[i2][j] * scale;
    __syncthreads();
    {
      float B2 = rthr[0][r];
#pragma unroll
      for (int j = 1; j < 8; j++) B2 = fmaxf(B2, rthr[j][r]);
      const float* srow = scb + (size_t)132 * r + 16 * p;
#pragma unroll 1
      for (int c = 0; c < 16; c++) {
        int cc = (c + r) & 15;
        float sv = srow[cc];
        if (sv > fmaxf(thr, B2))
          insert32vi(rtv, rti, sv, mt + 16 * p + cc, thr);
      }
      rthr[p][r] = thr;
    }
  }
  __syncthreads();
  {
    float* mvals = &ks[0][0];
#pragma unroll
    for (int k = 0; k < 32; k++) {
      int cc = (k + r) & 31;
      mvals[(size_t)260 * r + 32 * p + cc] = rtv[k];
      midx[(size_t)260 * r + 32 * p + cc] = (unsigned short)rti[k];
    }
  }
  __syncthreads();
  if (t < 32) {
    const float* mvals = &ks[0][0];
#pragma unroll 1
    for (int c = 0; c < 224; c++) {
      int cc = c + r; if (cc >= 224) cc -= 224;
      float sv = mvals[(size_t)260 * r + 32 + cc];
      if (sv > thr)
        insert32vi(rtv, rti, sv, (int)midx[(size_t)260 * r + 32 + cc], thr);
    }
    size_t rowg = ((size_t)b * HH + h) * NN + it * 32 + r;
#pragma unroll
    for (int k = 0; k < 32; k++) {
      topv[rowg * TOPKK + k] = rtv[k];
      topi[rowg * TOPKK + k] = rti[k];
    }
  }
}

// ---------------- flash attention (+ optional kNN memory logits) ----------
__global__ __launch_bounds__(256) void attn_kernel(const float* __restrict__ q,
                                                   const float* __restrict__ k,
                                                   const float* __restrict__ v,
                                                   __bf16* __restrict__ ao,
                                                   const float* __restrict__ topv,
                                                   const int* __restrict__ topi,
                                                   const float* __restrict__ mem_v,
                                                   int knn) {
  int bi = blockIdx.x, h = blockIdx.y, b = blockIdx.z;
  __shared__ float ks[64][64];
  __shared__ float vs[64][64];
  __shared__ float sc[64][65];
  __shared__ float marr[64], larr[64], aarr[64];
  __shared__ int pidx[64][33];
  const float scale = 0.125f;
  int t = threadIdx.x;
  int r = t & 63;
  int w = t >> 6;
  int i0 = bi * 64;
  int iglob = i0 + r;

  float qreg[64];
  {
    const float* qp = q + ((size_t)(b * NN) + iglob) * DD + h * DHH;
#pragma unroll
    for (int d4 = 0; d4 < 64; d4 += 4) {
      float4 a = *(const float4*)(qp + d4);
      qreg[d4] = a.x * scale; qreg[d4 + 1] = a.y * scale;
      qreg[d4 + 2] = a.z * scale; qreg[d4 + 3] = a.w * scale;
    }
  }
  if (t < 64) { marr[t] = -INFINITY; larr[t] = 0.f; }
  float acc[16] = {};
  int ntiles = bi + 1;
  for (int jt = 0; jt < ntiles; jt++) {
    __syncthreads();
#pragma unroll
    for (int i = 0; i < 4; i++) {
      int lin = i * 256 + t;
      int row = lin >> 4, col = (lin & 15) * 4;
      size_t goff = ((size_t)(b * NN) + jt * 64 + row) * DD + h * DHH + col;
      *(float4*)&ks[row][col] = *(const float4*)(k + goff);
      *(float4*)&vs[row][col] = *(const float4*)(v + goff);
    }
    __syncthreads();
    {
      float s[16] = {};
#pragma unroll
      for (int d4 = 0; d4 < 64; d4 += 4) {
#pragma unroll
        for (int j = 0; j < 16; j++) {
          float4 k4 = *(const float4*)&ks[w * 16 + j][d4];
          s[j] += qreg[d4] * k4.x + qreg[d4 + 1] * k4.y +
                  qreg[d4 + 2] * k4.z + qreg[d4 + 3] * k4.w;
        }
      }
#pragma unroll
      for (int j = 0; j < 16; j++) sc[r][w * 16 + j] = s[j];
    }
    __syncthreads();
    {
      int lane = t & 63;
      for (int rr = w * 16; rr < w * 16 + 16; rr++) {
        int ig = i0 + rr;
        int jg = jt * 64 + lane;
        float s = sc[rr][lane];
        if (jg > ig) s = -INFINITY;
        float m_old = marr[rr];
        float tm = s;
#pragma unroll
        for (int m = 32; m; m >>= 1) tm = fmaxf(tm, __shfl_xor(tm, m, 64));
        float m_new = fmaxf(m_old, tm);
        float p = __expf(s - m_new);
        float ts = p;
#pragma unroll
        for (int m = 32; m; m >>= 1) ts += __shfl_xor(ts, m, 64);
        float alpha = __expf(m_old - m_new);
        sc[rr][lane] = p;
        if (lane == 0) {
          marr[rr] = m_new; larr[rr] = larr[rr] * alpha + ts; aarr[rr] = alpha;
        }
      }
    }
    __syncthreads();
    {
      float al = aarr[r];
#pragma unroll
      for (int dd = 0; dd < 16; dd++) acc[dd] *= al;
      for (int j = 0; j < 64; j++) {
        float p = sc[r][j];
        const float* vrow = &vs[j][w * 16];
#pragma unroll
        for (int dd = 0; dd < 16; dd += 4) {
          float4 v4 = *(const float4*)(vrow + dd);
          acc[dd] += p * v4.x; acc[dd + 1] += p * v4.y;
          acc[dd + 2] += p * v4.z; acc[dd + 3] += p * v4.w;
        }
      }
    }
  }
  if (knn) {
    __syncthreads();
    {
      int lane = t & 63;
      size_t rowbase = ((size_t)b * HH + h) * NN + i0;
      for (int rr = w * 16; rr < w * 16 + 16; rr++) {
        float s = (lane < TOPKK) ? topv[(rowbase + rr) * TOPKK + lane] : -INFINITY;
        float m_old = marr[rr];
        float tm = s;
#pragma unroll
        for (int m = 32; m; m >>= 1) tm = fmaxf(tm, __shfl_xor(tm, m, 64));
        float m_new = fmaxf(m_old, tm);
        float p = __expf(s - m_new);
        float ts = p;
#pragma unroll
        for (int m = 32; m; m >>= 1) ts += __shfl_xor(ts, m, 64);
        float alpha = __expf(m_old - m_new);
        sc[rr][lane] = p;
        if (lane < TOPKK) pidx[rr][lane] = topi[(rowbase + rr) * TOPKK + lane];
        if (lane == 0) {
          marr[rr] = m_new; larr[rr] = larr[rr] * alpha + ts; aarr[rr] = alpha;
        }
      }
    }
    __syncthreads();
    {
      float al = aarr[r];
#pragma unroll
      for (int dd = 0; dd < 16; dd++) acc[dd] *= al;
      const float* mvb = mem_v + (size_t)b * MEMM * DHH;
      for (int kk = 0; kk < TOPKK; kk++) {
        float p = sc[r][kk];
        const float* mrow = mvb + (size_t)pidx[r][kk] * DHH + w * 16;
#pragma unroll
        for (int dd = 0; dd < 16; dd += 4) {
          float4 m4 = *(const float4*)(mrow + dd);
          acc[dd] += p * m4.x; acc[dd + 1] += p * m4.y;
          acc[dd + 2] += p * m4.z; acc[dd + 3] += p * m4.w;
        }
      }
    }
  }
  {
    float linv = 1.0f / larr[r];
    __bf16* aop = ao + ((size_t)(b * NN) + iglob) * DD + h * DHH + w * 16;
#pragma unroll
    for (int dd = 0; dd < 16; dd++) aop[dd] = (__bf16)(acc[dd] * linv);
  }
}

// ---------------- host ----------------
extern "C" void kernel_launch(void* const* d_in, const int* in_sizes, int n_in,
                              void* d_out, int out_size, void* d_ws, size_t ws_size,
                              hipStream_t stream) {
  const float* x_in  = (const float*)d_in[0];
  const float* Wq    = (const float*)d_in[1];
  const float* Wk    = (const float*)d_in[2];
  const float* Wv    = (const float*)d_in[3];
  const float* Wo    = (const float*)d_in[4];
  const float* ln1_s = (const float*)d_in[5];
  const float* ln1_b = (const float*)d_in[6];
  const float* ln2_s = (const float*)d_in[7];
  const float* ln2_b = (const float*)d_in[8];
  const float* W1    = (const float*)d_in[9];
  const float* W2    = (const float*)d_in[10];
  const float* lnf_s = (const float*)d_in[11];
  const float* lnf_b = (const float*)d_in[12];
  const float* mem_k = (const float*)d_in[13];
  const float* mem_v = (const float*)d_in[14];

  float* ws  = (float*)d_ws;
  float*  xb    = ws;
  float*  qb    = ws + 2097152;
  float*  kb    = ws + 4194304;
  float*  vb    = ws + 6291456;
  __bf16* hb16  = (__bf16*)(ws + 8388608);
  __bf16* ao16  = (__bf16*)(ws + 9437184);
  __bf16* wqT   = (__bf16*)(ws + 10485760);
  __bf16* wkT   = (__bf16*)(ws + 10616832);
  __bf16* wvT   = (__bf16*)(ws + 10747904);
  __bf16* woT   = (__bf16*)(ws + 10878976);
  __bf16* w1T   = (__bf16*)(ws + 11010048);
  __bf16* w2T   = (__bf16*)(ws + 11534336);
  float*  tvb   = ws + 12058624;
  int*    tib   = (int*)(ws + 13107200);
  __bf16* ffb16 = (__bf16*)(ws + 2097152);

  // big-ws path: materialized score matrix S (B*H*N*MEM fp32 = 512 MB)
  const size_t base_floats = 14155776;
  const size_t s_floats = (size_t)BB * HH * NN * MEMM;
  bool bigws = ws_size >= (base_floats + s_floats) * sizeof(float);
  float* Sb = ws + base_floats;

  dim3 blk(256);
  const size_t DD2 = (size_t)DD * DD;
  for (int l = 0; l < DEPTHH; l++) {
    const float* xcur = (l == 0) ? x_in : xb;
    transpose_bf16_kernel<<<dim3(16, 16), blk, 0, stream>>>(Wq + l * DD2, wqT, DD, DD);
    transpose_bf16_kernel<<<dim3(16, 16), blk, 0, stream>>>(Wk + l * DD2, wkT, DD, DD);
    transpose_bf16_kernel<<<dim3(16, 16), blk, 0, stream>>>(Wv + l * DD2, wvT, DD, DD);
    transpose_bf16_kernel<<<dim3(16, 16), blk, 0, stream>>>(Wo + l * DD2, woT, DD, DD);
    transpose_bf16_kernel<<<dim3(64, 16), blk, 0, stream>>>(W1 + (size_t)l * DD * FFF, w1T, DD, FFF);
    transpose_bf16_kernel<<<dim3(16, 64), blk, 0, stream>>>(W2 + (size_t)l * FFF * DD, w2T, FFF, DD);

    ln_kernel<1><<<NT, blk, 0, stream>>>(xcur, ln1_s + l * DD, ln1_b + l * DD, hb16);
    gemm_mfma<0, 0><<<dim3(8, 32), blk, 0, stream>>>(hb16, wqT, nullptr, qb, NT, DD, DD);
    gemm_mfma<0, 0><<<dim3(8, 32), blk, 0, stream>>>(hb16, wkT, nullptr, kb, NT, DD, DD);
    gemm_mfma<0, 0><<<dim3(8, 32), blk, 0, stream>>>(hb16, wvT, nullptr, vb, NT, DD, DD);
    int mi = (l == 3) ? 0 : ((l == 4) ? 1 : -1);
    if (mi >= 0) {
      const float* mk = mem_k + (size_t)mi * BB * MEMM * DHH;
      if (bigws) {
        knn_score_kernel<<<dim3(16, 8, 8), blk, 0, stream>>>(qb, mk, Sb);
        knn_select_kernel<<<dim3(BB * HH * NN / 4), blk, 0, stream>>>(Sb, tvb, tib);
      } else {
        knn_topk_kernel<<<dim3(16, 8, 8), blk, 0, stream>>>(qb, mk, tvb, tib);
      }
    }
    attn_kernel<<<dim3(8, 8, 8), blk, 0, stream>>>(
        qb, kb, vb, ao16, tvb, tib,
        mem_v + (size_t)(mi < 0 ? 0 : mi) * BB * MEMM * DHH, mi >= 0 ? 1 : 0);
    gemm_mfma<2, 0><<<dim3(8, 32), blk, 0, stream>>>(ao16, woT, xcur, xb, NT, DD, DD);
    ln_kernel<1><<<NT, blk, 0, stream>>>(xb, ln2_s + l * DD, ln2_b + l * DD, hb16);
    gemm_mfma<1, 1><<<dim3(32, 32), blk, 0, stream>>>(hb16, w1T, nullptr, ffb16, NT, FFF, DD);
    gemm_mfma<2, 0><<<dim3(8, 32), blk, 0, stream>>>(ffb16, w2T, xb, xb, NT, DD, FFF);
  }
  ln_kernel<0><<<NT, blk, 0, stream>>>(xb, lnf_s, lnf_b, (float*)d_out);
}